// Round 5
// baseline (437.959 us; speedup 1.0000x reference)
//
#include <hip/hip_runtime.h>
#include <math.h>

#define HDIM 256
#define FDIM 768
#define BM 128
#define BK 32

typedef __attribute__((ext_vector_type(8))) short short8;
typedef __attribute__((ext_vector_type(4))) float f32x4;
typedef __attribute__((ext_vector_type(4))) unsigned short us4;

__device__ __forceinline__ unsigned short f2bf(float f) {
  unsigned int u = __float_as_uint(f);
  unsigned int r = (u + 0x7FFFu + ((u >> 16) & 1u)) >> 16;
  return (unsigned short)r;
}
__device__ __forceinline__ float bf2f(unsigned short b) {
  return __uint_as_float(((unsigned int)b) << 16);
}

__device__ __forceinline__ void gload_lds16(const void* g, void* l) {
  __builtin_amdgcn_global_load_lds(
      (const __attribute__((address_space(1))) void*)g,
      (__attribute__((address_space(3))) void*)l, 16, 0, 0);
}

// device-scope global barrier; bar[idx]=counter, bar[idx+8]=release flag.
// All zeroed by memset before launch. Grid must be fully co-resident.
__device__ __forceinline__ void gbar(int* bar, int idx, int nb) {
  __syncthreads();
  if (threadIdx.x == 0) {
    __threadfence();
    if (__hip_atomic_fetch_add(bar + idx, 1, __ATOMIC_ACQ_REL,
                               __HIP_MEMORY_SCOPE_AGENT) == nb - 1) {
      __hip_atomic_store(bar + idx + 8, 1, __ATOMIC_RELEASE,
                         __HIP_MEMORY_SCOPE_AGENT);
    } else {
      while (!__hip_atomic_load(bar + idx + 8, __ATOMIC_ACQUIRE,
                                __HIP_MEMORY_SCOPE_AGENT))
        __builtin_amdgcn_s_sleep(8);
    }
    __threadfence();
  }
  __syncthreads();
}

// ---------------- setup: prep roles + hist -> scan -> scatter, ONE dispatch ----------------
// grid MUST be 256 blocks x 256 threads (co-resident: 1 block/CU).

__global__ __launch_bounds__(256, 2) void k_setup(
    const float* __restrict__ We1, const float* __restrict__ ae1,
    const float* __restrict__ We2, const float* __restrict__ ae2,
    float* __restrict__ v1, float* __restrict__ v2,
    const float* __restrict__ W1, unsigned short* __restrict__ W1t,
    const float* __restrict__ W2, unsigned short* __restrict__ W2t,
    const int* __restrict__ dstArr, int* __restrict__ cnt, int* __restrict__ bar,
    int* __restrict__ offsets, int* __restrict__ cursor,
    int* __restrict__ elist, int* __restrict__ bsums, int N, int E) {
  __shared__ int s[256];
  __shared__ int s2[256];
  const int bid = blockIdx.x;
  const int t = threadIdx.x;
  const int NB = 256;

  // ---- phase A: prep roles + hist ----
  if (bid < 128) {
    int wv = t >> 6, lane = t & 63;
    #pragma unroll
    for (int i = 0; i < 3; ++i) {
      int row = bid * 12 + wv * 3 + i;  // 0..1535
      const float* W = (row < FDIM) ? We1 : We2;
      const float* a = (row < FDIM) ? ae1 : ae2;
      int r = (row < FDIM) ? row : row - FDIM;
      float4 w4 = *(const float4*)&W[(size_t)r * HDIM + lane * 4];
      float4 av = *(const float4*)&a[lane * 4];
      float p = w4.x * av.x + w4.y * av.y + w4.z * av.z + w4.w * av.w;
      #pragma unroll
      for (int off = 32; off; off >>= 1) p += __shfl_down(p, off, 64);
      if (lane == 0) ((row < FDIM) ? v1 : v2)[r] = p;
    }
  } else if (bid < 192) {
    int nn0 = (bid - 128) * 4;
    for (int q = 0; q < 4; ++q) {
      int nn = nn0 + q;
      for (int k = t; k < FDIM; k += 256)
        W1t[(size_t)nn * FDIM + k] = f2bf(W1[(size_t)k * HDIM + nn]);
    }
  } else {
    int nn0 = (bid - 192) * 4;
    for (int q = 0; q < 4; ++q) {
      int nn = nn0 + q;
      for (int k = t; k < HDIM; k += 256)
        W2t[(size_t)nn * HDIM + k] = f2bf(W2[(size_t)k * HDIM + nn]);
    }
  }
  for (int e = bid * 256 + t; e < E; e += NB * 256)
    atomicAdd(&cnt[dstArr[e]], 1);
  gbar(bar, 0, NB);

  // ---- phase B: per-block inclusive scan of cnt ----
  const int nb = (N + 255) / 256;
  int v0 = 0;
  if (bid < nb) {
    int i = bid * 256 + t;
    v0 = (i < N) ? cnt[i] : 0;
    s[t] = v0;
    __syncthreads();
    for (int off = 1; off < 256; off <<= 1) {
      int tv = (t >= off) ? s[t - off] : 0;
      __syncthreads();
      s[t] += tv;
      __syncthreads();
    }
    if (t == 255) bsums[bid] = s[255];
  }
  gbar(bar, 1, NB);

  // ---- phase C: block 0 scans block sums (exclusive) ----
  if (bid == 0) {
    int vv = (t < nb) ? bsums[t] : 0;
    s2[t] = vv;
    __syncthreads();
    for (int off = 1; off < 256; off <<= 1) {
      int tv = (t >= off) ? s2[t - off] : 0;
      __syncthreads();
      s2[t] += tv;
      __syncthreads();
    }
    if (t < nb) bsums[t] = s2[t] - vv;
  }
  gbar(bar, 2, NB);

  // ---- phase D: write offsets + cursor ----
  if (bid < nb) {
    int i = bid * 256 + t;
    if (i < N) {
      int base = bsums[bid];
      int incl = s[t] + base;
      offsets[i + 1] = incl;
      cursor[i] = incl - v0;
      if (i == 0) offsets[0] = 0;
    }
  }
  gbar(bar, 3, NB);

  // ---- phase E: scatter ----
  for (int e = bid * 256 + t; e < E; e += NB * 256) {
    int p = atomicAdd(&cursor[dstArr[e]], 1);
    elist[p] = e;
  }
}

// ---------------- GEMM body: C[M][HDIM] = A@Bt^T, fused row-dots ----------------
// BM=128, BN=256(full), BK=32, 512 threads = 8 waves (2m x 4n), wave tile 64x64.
// LDS chunk-major: As p=c*2048+m*16 (8KB), Bs p=c*4096+n*16 (16KB), partials 4KB.

template <bool AF32, bool COUTBF>
__device__ __forceinline__ void gemm_body(unsigned char* lds,
                                          const void* __restrict__ Ain,
                                          const unsigned short* __restrict__ Bt,
                                          void* __restrict__ Cout,
                                          float* __restrict__ sOut,
                                          float* __restrict__ dOut,
                                          const float* __restrict__ a_src,
                                          const float* __restrict__ a_dst,
                                          int M, int K, int tile) {
  unsigned char* As = lds;
  unsigned char* Bs = lds + 8192;
  float* partS = (float*)(lds + 24576);         // [4][128]
  float* partD = (float*)(lds + 24576 + 2048);  // [4][128]
  const int t = threadIdx.x;
  const int l = t & 63;
  const int w = t >> 6;
  const int wm = w >> 2, wn = w & 3;
  const int bm = tile * BM;

  f32x4 acc[4][4] = {};

  int rowA = bm + (t & 127);
  if (rowA >= M) rowA = M - 1;
  const int cA = t >> 7;
  int rowAr = bm + (t >> 2);
  if (rowAr >= M) rowAr = M - 1;
  const int kbAr = t & 3;
  const int sAr = kbAr * 2048 + (t >> 2) * 16;
  const int nB = t & 255;
  const int cB0 = t >> 8;
  const int cB1 = 2 + (t >> 8);

  int aAddr[4], bAddr[4];
  #pragma unroll
  for (int mt = 0; mt < 4; ++mt) {
    int m = wm * 64 + mt * 16 + (l & 15);
    aAddr[mt] = (l >> 4) * 2048 + m * 16;
  }
  #pragma unroll
  for (int nt = 0; nt < 4; ++nt) {
    int nn = wn * 64 + nt * 16 + (l & 15);
    bAddr[nt] = (l >> 4) * 4096 + nn * 16;
  }

  const int nsteps = K / BK;
  for (int ks = 0; ks < nsteps; ++ks) {
    const int k0 = ks * BK;
    __syncthreads();
    if (AF32) {
      const float* A = (const float*)Ain;
      const float* p = A + (size_t)rowAr * K + k0 + kbAr * 8;
      float4 f0 = *(const float4*)p;
      float4 f1 = *(const float4*)(p + 4);
      short8 hv;
      hv[0] = (short)f2bf(f0.x); hv[1] = (short)f2bf(f0.y);
      hv[2] = (short)f2bf(f0.z); hv[3] = (short)f2bf(f0.w);
      hv[4] = (short)f2bf(f1.x); hv[5] = (short)f2bf(f1.y);
      hv[6] = (short)f2bf(f1.z); hv[7] = (short)f2bf(f1.w);
      *(short8*)(As + sAr) = hv;
    } else {
      const unsigned short* A = (const unsigned short*)Ain;
      gload_lds16(A + (size_t)rowA * K + k0 + cA * 8, As + t * 16);
    }
    gload_lds16(Bt + (size_t)nB * K + k0 + cB0 * 8, Bs + t * 16);
    gload_lds16(Bt + (size_t)nB * K + k0 + cB1 * 8, Bs + 8192 + t * 16);
    __syncthreads();

    short8 af[4], bfr[4];
    #pragma unroll
    for (int mt = 0; mt < 4; ++mt) af[mt] = *(const short8*)(As + aAddr[mt]);
    #pragma unroll
    for (int nt = 0; nt < 4; ++nt) bfr[nt] = *(const short8*)(Bs + bAddr[nt]);
    #pragma unroll
    for (int mt = 0; mt < 4; ++mt)
      #pragma unroll
      for (int nt = 0; nt < 4; ++nt)
        acc[mt][nt] = __builtin_amdgcn_mfma_f32_16x16x32_bf16(af[mt], bfr[nt], acc[mt][nt], 0, 0, 0);
  }

  // epilogue: C store + fused row-dots
  float asv[4], adv[4];
  #pragma unroll
  for (int nt = 0; nt < 4; ++nt) {
    int col = wn * 64 + nt * 16 + (l & 15);
    asv[nt] = a_src[col];
    adv[nt] = a_dst[col];
  }
  #pragma unroll
  for (int mt = 0; mt < 4; ++mt) {
    int rloc = wm * 64 + mt * 16 + ((l >> 4) << 2);
    #pragma unroll
    for (int r = 0; r < 4; ++r) {
      int row = bm + rloc + r;
      float ps = 0.f, pd = 0.f;
      #pragma unroll
      for (int nt = 0; nt < 4; ++nt) {
        float v = acc[mt][nt][r];
        if (row < M) {
          int col = wn * 64 + nt * 16 + (l & 15);
          if (COUTBF)
            ((unsigned short*)Cout)[(size_t)row * HDIM + col] = f2bf(v);
          else
            ((float*)Cout)[(size_t)row * HDIM + col] = v;
        }
        ps += v * asv[nt];
        pd += v * adv[nt];
      }
      #pragma unroll
      for (int off = 1; off < 16; off <<= 1) {
        ps += __shfl_xor(ps, off, 64);
        pd += __shfl_xor(pd, off, 64);
      }
      if ((l & 15) == 0) {
        partS[wn * 128 + rloc + r] = ps;
        partD[wn * 128 + rloc + r] = pd;
      }
    }
  }
  __syncthreads();
  if (t < 128) {
    int row = bm + t;
    if (row < M) {
      sOut[row] = partS[t] + partS[128 + t] + partS[256 + t] + partS[384 + t];
      dOut[row] = partD[t] + partD[128 + t] + partD[256 + t] + partD[384 + t];
    }
  }
}

// ---------------- edge-alpha body (8 edges per 512-thread block) ----------------

__device__ __forceinline__ void edge_body(unsigned char* lds,
                                          const float* __restrict__ ea,
                                          const float* __restrict__ v1,
                                          const float* __restrict__ v2,
                                          float* __restrict__ o1,
                                          float* __restrict__ o2, int E, int ebid) {
  float* sv1 = (float*)lds;
  float* sv2 = (float*)(lds + 3072);
  for (int i = threadIdx.x; i < FDIM; i += 512) { sv1[i] = v1[i]; sv2[i] = v2[i]; }
  __syncthreads();
  int e = ebid * 8 + (threadIdx.x >> 6);
  if (e >= E) return;
  int lane = threadIdx.x & 63;
  const float* row = ea + (size_t)e * FDIM;
  float p1 = 0.f, p2 = 0.f;
  #pragma unroll
  for (int t = 0; t < 3; ++t) {
    int idx = t * 256 + lane * 4;
    float4 x = *(const float4*)&row[idx];
    float4 a = *(const float4*)&sv1[idx];
    float4 b = *(const float4*)&sv2[idx];
    p1 += x.x * a.x + x.y * a.y + x.z * a.z + x.w * a.w;
    p2 += x.x * b.x + x.y * b.y + x.z * b.z + x.w * b.w;
  }
  #pragma unroll
  for (int off = 32; off; off >>= 1) {
    p1 += __shfl_down(p1, off, 64);
    p2 += __shfl_down(p2, off, 64);
  }
  if (lane == 0) { o1[e] = p1; o2[e] = p2; }
}

// ---------------- fat kernel 1: GEMM1 tiles || edge-alpha blocks ----------------

__global__ __launch_bounds__(512) void k_fat1(
    const float* __restrict__ x, const unsigned short* __restrict__ W1t,
    unsigned short* __restrict__ xl1b, float* __restrict__ sArr, float* __restrict__ dArr,
    const float* __restrict__ as1, const float* __restrict__ ad1, int M,
    const float* __restrict__ ea, const float* __restrict__ v1,
    const float* __restrict__ v2, float* __restrict__ ae1Arr,
    float* __restrict__ ae2Arr, int E, int nGemm) {
  __shared__ unsigned char lds[28672];
  if ((int)blockIdx.x < nGemm)
    gemm_body<true, true>(lds, x, W1t, xl1b, sArr, dArr, as1, ad1, M, FDIM, blockIdx.x);
  else
    edge_body(lds, ea, v1, v2, ae1Arr, ae2Arr, E, blockIdx.x - nGemm);
}

__global__ __launch_bounds__(512) void k_gemm2(
    const unsigned short* __restrict__ hb, const unsigned short* __restrict__ W2t,
    float* __restrict__ xl2, float* __restrict__ sArr, float* __restrict__ dArr,
    const float* __restrict__ as2, const float* __restrict__ ad2, int M) {
  __shared__ unsigned char lds[28672];
  gemm_body<false, false>(lds, hb, W2t, xl2, sArr, dArr, as2, ad2, M, HDIM, blockIdx.x);
}

// ---------------- aggregate: fused logits + online softmax + weighted gather ----------------

template <int INBF, int OUTBF, int RELU>
__global__ __launch_bounds__(256) void k_aggregate(const void* __restrict__ xlv,
                                                   const float* __restrict__ sArr,
                                                   const float* __restrict__ dArr,
                                                   const float* __restrict__ aeArr,
                                                   const int* __restrict__ src,
                                                   const int* __restrict__ offsets,
                                                   const int* __restrict__ elist,
                                                   const float* __restrict__ bias,
                                                   void* __restrict__ outv, int n) {
  int node = blockIdx.x * 4 + (threadIdx.x >> 6);
  if (node >= n) return;
  int lane = threadIdx.x & 63;
  int beg = offsets[node], end = offsets[node + 1];
  float dnode = dArr[node];
  float run_m = -1e30f, run_den = 0.f;
  float a0 = 0.f, a1 = 0.f, a2 = 0.f, a3 = 0.f;
  for (int c0 = beg; c0 < end; c0 += 64) {
    int j = c0 + lane;
    float al = -1e30f;
    int sj = 0;
    if (j < end) {
      int e = elist[j];
      sj = src[e];
      float a = sArr[sj] + dnode + aeArr[e];
      al = (a > 0.f) ? a : 0.2f * a;
    }
    float cm = al;
    #pragma unroll
    for (int off = 32; off; off >>= 1) cm = fmaxf(cm, __shfl_xor(cm, off, 64));
    float new_m = fmaxf(run_m, cm);
    float ev = (j < end) ? expf(al - new_m) : 0.f;
    float csum = ev;
    #pragma unroll
    for (int off = 32; off; off >>= 1) csum += __shfl_xor(csum, off, 64);
    float scale = expf(run_m - new_m);
    run_den = run_den * scale + csum;
    a0 *= scale; a1 *= scale; a2 *= scale; a3 *= scale;
    int cdeg = end - c0;
    if (cdeg > 64) cdeg = 64;
    for (int q = 0; q < cdeg; ++q) {
      float wgt = __shfl(ev, q, 64);
      int sq = __shfl(sj, q, 64);
      if (INBF) {
        us4 v = *(const us4*)((const unsigned short*)xlv + (size_t)sq * HDIM + lane * 4);
        a0 += wgt * bf2f(v[0]); a1 += wgt * bf2f(v[1]);
        a2 += wgt * bf2f(v[2]); a3 += wgt * bf2f(v[3]);
      } else {
        float4 v = *(const float4*)((const float*)xlv + (size_t)sq * HDIM + lane * 4);
        a0 += wgt * v.x; a1 += wgt * v.y; a2 += wgt * v.z; a3 += wgt * v.w;
      }
    }
    run_m = new_m;
  }
  float inv = (end > beg) ? 1.f / run_den : 0.f;
  float4 bv = *(const float4*)(bias + lane * 4);
  float o0 = a0 * inv + bv.x, o1 = a1 * inv + bv.y;
  float o2 = a2 * inv + bv.z, o3 = a3 * inv + bv.w;
  if (RELU) {
    o0 = fmaxf(o0, 0.f); o1 = fmaxf(o1, 0.f);
    o2 = fmaxf(o2, 0.f); o3 = fmaxf(o3, 0.f);
  }
  if (OUTBF) {
    us4 ov;
    ov[0] = f2bf(o0); ov[1] = f2bf(o1); ov[2] = f2bf(o2); ov[3] = f2bf(o3);
    *(us4*)((unsigned short*)outv + (size_t)node * HDIM + lane * 4) = ov;
  } else {
    *(float4*)((float*)outv + (size_t)node * HDIM + lane * 4) =
        make_float4(o0, o1, o2, o3);
  }
}

// ---------------- prediction head ----------------

__global__ void k_head(const float* __restrict__ titles, const int* __restrict__ nodes,
                       const float* __restrict__ Wp, const float* __restrict__ bp,
                       float* __restrict__ out, int Bn) {
  int b = blockIdx.x * 4 + (threadIdx.x >> 6);
  if (b >= Bn) return;
  int lane = threadIdx.x & 63;
  const float* r0 = titles + (size_t)nodes[b] * HDIM;
  const float* r1 = titles + (size_t)nodes[Bn + b] * HDIM;
  float s0 = 0.f, s1 = 0.f, s2 = 0.f;
  #pragma unroll
  for (int i = 0; i < 4; ++i) {
    int h = lane + 64 * i;
    float c = r0[h] * r1[h];
    s0 += c * Wp[h * 3 + 0];
    s1 += c * Wp[h * 3 + 1];
    s2 += c * Wp[h * 3 + 2];
  }
  #pragma unroll
  for (int off = 32; off; off >>= 1) {
    s0 += __shfl_down(s0, off, 64);
    s1 += __shfl_down(s1, off, 64);
    s2 += __shfl_down(s2, off, 64);
  }
  if (lane == 0) {
    out[b * 3 + 0] = s0 + bp[0];
    out[b * 3 + 1] = s1 + bp[1];
    out[b * 3 + 2] = s2 + bp[2];
  }
}

// ---------------- launch ----------------

extern "C" void kernel_launch(void* const* d_in, const int* in_sizes, int n_in,
                              void* d_out, int out_size, void* d_ws, size_t ws_size,
                              hipStream_t stream) {
  const float* x         = (const float*)d_in[0];
  const float* edge_attr = (const float*)d_in[1];
  const float* W1  = (const float*)d_in[2];
  const float* as1 = (const float*)d_in[3];
  const float* ad1 = (const float*)d_in[4];
  const float* We1 = (const float*)d_in[5];
  const float* ae1 = (const float*)d_in[6];
  const float* b1  = (const float*)d_in[7];
  const float* W2  = (const float*)d_in[8];
  const float* as2 = (const float*)d_in[9];
  const float* ad2 = (const float*)d_in[10];
  const float* We2 = (const float*)d_in[11];
  const float* ae2 = (const float*)d_in[12];
  const float* b2  = (const float*)d_in[13];
  const float* Wp  = (const float*)d_in[14];
  const float* bp  = (const float*)d_in[15];
  const int* edge_index = (const int*)d_in[16];
  const int* nodes      = (const int*)d_in[17];

  const int N  = in_sizes[0] / FDIM;
  const int E  = in_sizes[16] / 2;
  const int Bn = in_sizes[17] / 2;
  const int* srcArr = edge_index;
  const int* dstArr = edge_index + E;

  char* w = (char*)d_ws;
  auto carve = [&](size_t bytes) -> void* {
    void* p = (void*)w;
    w += (bytes + 255) & ~(size_t)255;
    return p;
  };
  float*          titles = (float*)carve(sizeof(float) * (size_t)N * HDIM);
  float*          xl2    = (float*)carve(sizeof(float) * (size_t)N * HDIM);
  unsigned short* xl1b   = (unsigned short*)carve(2 * (size_t)N * HDIM);
  unsigned short* hb     = (unsigned short*)carve(2 * (size_t)N * HDIM);
  unsigned short* W1t    = (unsigned short*)carve(2 * (size_t)FDIM * HDIM);
  unsigned short* W2t    = (unsigned short*)carve(2 * (size_t)HDIM * HDIM);
  float* ae1Arr = (float*)carve(sizeof(float) * E);
  float* ae2Arr = (float*)carve(sizeof(float) * E);
  float* sArr = (float*)carve(sizeof(float) * N);
  float* dArr = (float*)carve(sizeof(float) * N);
  float* v1 = (float*)carve(sizeof(float) * FDIM);
  float* v2 = (float*)carve(sizeof(float) * FDIM);
  int* cntbar  = (int*)carve(sizeof(int) * (N + 64));  // cnt[N] + bar[64], one memset
  int* offsets = (int*)carve(sizeof(int) * (N + 1));
  int* cursor  = (int*)carve(sizeof(int) * N);
  int* elist   = (int*)carve(sizeof(int) * E);
  int* bsums   = (int*)carve(sizeof(int) * 512);

  int* cnt = cntbar;
  int* bar = cntbar + N;

  const int nGemm = (N + BM - 1) / BM;
  const int nEdge = (E + 7) / 8;

  // zero cnt + barrier state (must be re-zeroed every launch for graph replay)
  hipMemsetAsync(cntbar, 0, sizeof(int) * (N + 64), stream);
  // fused setup: compute_v + cvtW + hist + scan + scatter
  k_setup<<<256, 256, 0, stream>>>(We1, ae1, We2, ae2, v1, v2, W1, W1t, W2, W2t,
                                   dstArr, cnt, bar, offsets, cursor, elist,
                                   bsums, N, E);

  // fat: GEMM1 (+row-dots, bf16 C) || edge-alpha (both layers)
  k_fat1<<<nGemm + nEdge, 512, 0, stream>>>(x, W1t, xl1b, sArr, dArr, as1, ad1, N,
                                            edge_attr, v1, v2, ae1Arr, ae2Arr, E, nGemm);
  // layer 1 aggregate (bf16 gather)
  k_aggregate<1, 1, 1><<<(N + 3) / 4, 256, 0, stream>>>(xl1b, sArr, dArr, ae1Arr, srcArr,
                                                        offsets, elist, b1, hb, N);
  // layer 2
  k_gemm2<<<nGemm, 512, 0, stream>>>(hb, W2t, xl2, sArr, dArr, as2, ad2, N);
  k_aggregate<0, 0, 0><<<(N + 3) / 4, 256, 0, stream>>>(xl2, sArr, dArr, ae2Arr, srcArr,
                                                        offsets, elist, b2, titles, N);
  // head
  k_head<<<(Bn + 3) / 4, 256, 0, stream>>>(titles, nodes, Wp, bp, (float*)d_out, Bn);
}

// Round 6
// 321.531 us; speedup vs baseline: 1.3621x; 1.3621x over previous
//
#include <hip/hip_runtime.h>
#include <math.h>

#define HDIM 256
#define FDIM 768
#define BM 128
#define BK 32

typedef __attribute__((ext_vector_type(8))) short short8;
typedef __attribute__((ext_vector_type(4))) float f32x4;
typedef __attribute__((ext_vector_type(4))) unsigned short us4;

__device__ __forceinline__ unsigned short f2bf(float f) {
  unsigned int u = __float_as_uint(f);
  unsigned int r = (u + 0x7FFFu + ((u >> 16) & 1u)) >> 16;
  return (unsigned short)r;
}
__device__ __forceinline__ float bf2f(unsigned short b) {
  return __uint_as_float(((unsigned int)b) << 16);
}

__device__ __forceinline__ void gload_lds16(const void* g, void* l) {
  __builtin_amdgcn_global_load_lds(
      (const __attribute__((address_space(1))) void*)g,
      (__attribute__((address_space(3))) void*)l, 16, 0, 0);
}

// ---------------- CSR build ----------------

__global__ void k_scan1(const int* __restrict__ cnt, int* __restrict__ offsets,
                        int* __restrict__ bsums, int n) {
  __shared__ int s[256];
  int i = blockIdx.x * 256 + threadIdx.x;
  int v = (i < n) ? cnt[i] : 0;
  s[threadIdx.x] = v;
  __syncthreads();
  for (int off = 1; off < 256; off <<= 1) {
    int t = (threadIdx.x >= off) ? s[threadIdx.x - off] : 0;
    __syncthreads();
    s[threadIdx.x] += t;
    __syncthreads();
  }
  if (i < n) offsets[i + 1] = s[threadIdx.x];
  if (threadIdx.x == 255) bsums[blockIdx.x] = s[255];
}

// merged: every block redundantly scans bsums (nb<=256), then applies its base
// and writes final offsets + cursor. Replaces separate scan2 + scan3 dispatches.
__global__ void k_scan23(int* __restrict__ offsets, int* __restrict__ cursor,
                         const int* __restrict__ bsums, int n) {
  __shared__ int s2[256];
  __shared__ int sBase;
  const int nb = (n + 255) / 256;
  const int t = threadIdx.x;
  const int bid = blockIdx.x;
  int vv = (t < nb) ? bsums[t] : 0;
  s2[t] = vv;
  __syncthreads();
  for (int off = 1; off < 256; off <<= 1) {
    int tv = (t >= off) ? s2[t - off] : 0;
    __syncthreads();
    s2[t] += tv;
    __syncthreads();
  }
  if (t == 0) sBase = (bid > 0) ? s2[bid - 1] : 0;
  __syncthreads();
  int base = sBase;
  int i = bid * 256 + t;
  if (i < n) {
    int v = offsets[i + 1] + base;
    offsets[i + 1] = v;
    if (i + 1 < n) cursor[i + 1] = v;
    if (i == 0) { offsets[0] = 0; cursor[0] = 0; }
  }
}

__global__ void k_scatter(const int* __restrict__ dst, int* __restrict__ cursor,
                          int* __restrict__ elist, int E) {
  int e = blockIdx.x * 256 + threadIdx.x;
  if (e < E) {
    int p = atomicAdd(&cursor[dst[e]], 1);
    elist[p] = e;
  }
}

// ---------------- prep: compute_v + cvtW1 + cvtW2 + hist, one dispatch ----------------

__global__ __launch_bounds__(256) void k_prep(
    const float* __restrict__ We1, const float* __restrict__ ae1,
    const float* __restrict__ We2, const float* __restrict__ ae2,
    float* __restrict__ v1, float* __restrict__ v2,
    const float* __restrict__ W1, unsigned short* __restrict__ W1t,
    const float* __restrict__ W2, unsigned short* __restrict__ W2t,
    const int* __restrict__ dstArr, int* __restrict__ cnt, int E) {
  int bid = blockIdx.x;
  if (bid < 384) {
    // v1 = We1 @ ae1, v2 = We2 @ ae2 (wave per row)
    int row = bid * 4 + (threadIdx.x >> 6);
    int lane = threadIdx.x & 63;
    const float* W = (row < FDIM) ? We1 : We2;
    const float* a = (row < FDIM) ? ae1 : ae2;
    int r = (row < FDIM) ? row : row - FDIM;
    float4 w = *(const float4*)&W[(size_t)r * HDIM + lane * 4];
    float4 av = *(const float4*)&a[lane * 4];
    float p = w.x * av.x + w.y * av.y + w.z * av.z + w.w * av.w;
    #pragma unroll
    for (int off = 32; off; off >>= 1) p += __shfl_down(p, off, 64);
    if (lane == 0) ((row < FDIM) ? v1 : v2)[r] = p;
  } else if (bid < 640) {
    int nn = bid - 384;
    for (int k = threadIdx.x; k < FDIM; k += 256)
      W1t[(size_t)nn * FDIM + k] = f2bf(W1[(size_t)k * HDIM + nn]);
  } else if (bid < 896) {
    int nn = bid - 640;
    for (int k = threadIdx.x; k < HDIM; k += 256)
      W2t[(size_t)nn * HDIM + k] = f2bf(W2[(size_t)k * HDIM + nn]);
  } else {
    int e = (bid - 896) * 256 + threadIdx.x;
    if (e < E) atomicAdd(&cnt[dstArr[e]], 1);
  }
}

// ---------------- GEMM body: C[M][HDIM] = A@Bt^T, fused row-dots ----------------
// BM=128, BN=256(full), BK=32, 512 threads = 8 waves (2m x 4n), wave tile 64x64.
// LDS chunk-major: As p=c*2048+m*16 (8KB), Bs p=c*4096+n*16 (16KB), partials 4KB.

template <bool AF32, bool COUTBF>
__device__ __forceinline__ void gemm_body(unsigned char* lds,
                                          const void* __restrict__ Ain,
                                          const unsigned short* __restrict__ Bt,
                                          void* __restrict__ Cout,
                                          float* __restrict__ sOut,
                                          float* __restrict__ dOut,
                                          const float* __restrict__ a_src,
                                          const float* __restrict__ a_dst,
                                          int M, int K, int tile) {
  unsigned char* As = lds;
  unsigned char* Bs = lds + 8192;
  float* partS = (float*)(lds + 24576);         // [4][128]
  float* partD = (float*)(lds + 24576 + 2048);  // [4][128]
  const int t = threadIdx.x;
  const int l = t & 63;
  const int w = t >> 6;
  const int wm = w >> 2, wn = w & 3;
  const int bm = tile * BM;

  f32x4 acc[4][4] = {};

  int rowA = bm + (t & 127);
  if (rowA >= M) rowA = M - 1;
  const int cA = t >> 7;
  int rowAr = bm + (t >> 2);
  if (rowAr >= M) rowAr = M - 1;
  const int kbAr = t & 3;
  const int sAr = kbAr * 2048 + (t >> 2) * 16;
  const int nB = t & 255;
  const int cB0 = t >> 8;
  const int cB1 = 2 + (t >> 8);

  int aAddr[4], bAddr[4];
  #pragma unroll
  for (int mt = 0; mt < 4; ++mt) {
    int m = wm * 64 + mt * 16 + (l & 15);
    aAddr[mt] = (l >> 4) * 2048 + m * 16;
  }
  #pragma unroll
  for (int nt = 0; nt < 4; ++nt) {
    int nn = wn * 64 + nt * 16 + (l & 15);
    bAddr[nt] = (l >> 4) * 4096 + nn * 16;
  }

  const int nsteps = K / BK;
  for (int ks = 0; ks < nsteps; ++ks) {
    const int k0 = ks * BK;
    __syncthreads();
    if (AF32) {
      const float* A = (const float*)Ain;
      const float* p = A + (size_t)rowAr * K + k0 + kbAr * 8;
      float4 f0 = *(const float4*)p;
      float4 f1 = *(const float4*)(p + 4);
      short8 hv;
      hv[0] = (short)f2bf(f0.x); hv[1] = (short)f2bf(f0.y);
      hv[2] = (short)f2bf(f0.z); hv[3] = (short)f2bf(f0.w);
      hv[4] = (short)f2bf(f1.x); hv[5] = (short)f2bf(f1.y);
      hv[6] = (short)f2bf(f1.z); hv[7] = (short)f2bf(f1.w);
      *(short8*)(As + sAr) = hv;
    } else {
      const unsigned short* A = (const unsigned short*)Ain;
      gload_lds16(A + (size_t)rowA * K + k0 + cA * 8, As + t * 16);
    }
    gload_lds16(Bt + (size_t)nB * K + k0 + cB0 * 8, Bs + t * 16);
    gload_lds16(Bt + (size_t)nB * K + k0 + cB1 * 8, Bs + 8192 + t * 16);
    __syncthreads();

    short8 af[4], bfr[4];
    #pragma unroll
    for (int mt = 0; mt < 4; ++mt) af[mt] = *(const short8*)(As + aAddr[mt]);
    #pragma unroll
    for (int nt = 0; nt < 4; ++nt) bfr[nt] = *(const short8*)(Bs + bAddr[nt]);
    #pragma unroll
    for (int mt = 0; mt < 4; ++mt)
      #pragma unroll
      for (int nt = 0; nt < 4; ++nt)
        acc[mt][nt] = __builtin_amdgcn_mfma_f32_16x16x32_bf16(af[mt], bfr[nt], acc[mt][nt], 0, 0, 0);
  }

  // epilogue: C store + fused row-dots
  float asv[4], adv[4];
  #pragma unroll
  for (int nt = 0; nt < 4; ++nt) {
    int col = wn * 64 + nt * 16 + (l & 15);
    asv[nt] = a_src[col];
    adv[nt] = a_dst[col];
  }
  #pragma unroll
  for (int mt = 0; mt < 4; ++mt) {
    int rloc = wm * 64 + mt * 16 + ((l >> 4) << 2);
    #pragma unroll
    for (int r = 0; r < 4; ++r) {
      int row = bm + rloc + r;
      float ps = 0.f, pd = 0.f;
      #pragma unroll
      for (int nt = 0; nt < 4; ++nt) {
        float v = acc[mt][nt][r];
        if (row < M) {
          int col = wn * 64 + nt * 16 + (l & 15);
          if (COUTBF)
            ((unsigned short*)Cout)[(size_t)row * HDIM + col] = f2bf(v);
          else
            ((float*)Cout)[(size_t)row * HDIM + col] = v;
        }
        ps += v * asv[nt];
        pd += v * adv[nt];
      }
      #pragma unroll
      for (int off = 1; off < 16; off <<= 1) {
        ps += __shfl_xor(ps, off, 64);
        pd += __shfl_xor(pd, off, 64);
      }
      if ((l & 15) == 0) {
        partS[wn * 128 + rloc + r] = ps;
        partD[wn * 128 + rloc + r] = pd;
      }
    }
  }
  __syncthreads();
  if (t < 128) {
    int row = bm + t;
    if (row < M) {
      sOut[row] = partS[t] + partS[128 + t] + partS[256 + t] + partS[384 + t];
      dOut[row] = partD[t] + partD[128 + t] + partD[256 + t] + partD[384 + t];
    }
  }
}

// ---------------- edge-alpha body (8 edges per 512-thread block) ----------------

__device__ __forceinline__ void edge_body(unsigned char* lds,
                                          const float* __restrict__ ea,
                                          const float* __restrict__ v1,
                                          const float* __restrict__ v2,
                                          float* __restrict__ o1,
                                          float* __restrict__ o2, int E, int ebid) {
  float* sv1 = (float*)lds;
  float* sv2 = (float*)(lds + 3072);
  for (int i = threadIdx.x; i < FDIM; i += 512) { sv1[i] = v1[i]; sv2[i] = v2[i]; }
  __syncthreads();
  int e = ebid * 8 + (threadIdx.x >> 6);
  if (e >= E) return;
  int lane = threadIdx.x & 63;
  const float* row = ea + (size_t)e * FDIM;
  float p1 = 0.f, p2 = 0.f;
  #pragma unroll
  for (int t = 0; t < 3; ++t) {
    int idx = t * 256 + lane * 4;
    float4 x = *(const float4*)&row[idx];
    float4 a = *(const float4*)&sv1[idx];
    float4 b = *(const float4*)&sv2[idx];
    p1 += x.x * a.x + x.y * a.y + x.z * a.z + x.w * a.w;
    p2 += x.x * b.x + x.y * b.y + x.z * b.z + x.w * b.w;
  }
  #pragma unroll
  for (int off = 32; off; off >>= 1) {
    p1 += __shfl_down(p1, off, 64);
    p2 += __shfl_down(p2, off, 64);
  }
  if (lane == 0) { o1[e] = p1; o2[e] = p2; }
}

// ---------------- fat kernel 1: GEMM1 tiles || edge-alpha blocks ----------------

__global__ __launch_bounds__(512) void k_fat1(
    const float* __restrict__ x, const unsigned short* __restrict__ W1t,
    unsigned short* __restrict__ xl1b, float* __restrict__ sArr, float* __restrict__ dArr,
    const float* __restrict__ as1, const float* __restrict__ ad1, int M,
    const float* __restrict__ ea, const float* __restrict__ v1,
    const float* __restrict__ v2, float* __restrict__ ae1Arr,
    float* __restrict__ ae2Arr, int E, int nGemm) {
  __shared__ unsigned char lds[28672];
  if ((int)blockIdx.x < nGemm)
    gemm_body<true, true>(lds, x, W1t, xl1b, sArr, dArr, as1, ad1, M, FDIM, blockIdx.x);
  else
    edge_body(lds, ea, v1, v2, ae1Arr, ae2Arr, E, blockIdx.x - nGemm);
}

__global__ __launch_bounds__(512) void k_gemm2(
    const unsigned short* __restrict__ hb, const unsigned short* __restrict__ W2t,
    unsigned short* __restrict__ xl2b, float* __restrict__ sArr, float* __restrict__ dArr,
    const float* __restrict__ as2, const float* __restrict__ ad2, int M) {
  __shared__ unsigned char lds[28672];
  gemm_body<false, true>(lds, hb, W2t, xl2b, sArr, dArr, as2, ad2, M, HDIM, blockIdx.x);
}

// ---------------- aggregate: fused logits + online softmax + weighted gather ----------------

template <int OUTBF, int RELU>
__global__ __launch_bounds__(256) void k_aggregate(const unsigned short* __restrict__ xlb,
                                                   const float* __restrict__ sArr,
                                                   const float* __restrict__ dArr,
                                                   const float* __restrict__ aeArr,
                                                   const int* __restrict__ src,
                                                   const int* __restrict__ offsets,
                                                   const int* __restrict__ elist,
                                                   const float* __restrict__ bias,
                                                   void* __restrict__ outv, int n) {
  int node = blockIdx.x * 4 + (threadIdx.x >> 6);
  if (node >= n) return;
  int lane = threadIdx.x & 63;
  int beg = offsets[node], end = offsets[node + 1];
  float dnode = dArr[node];
  float run_m = -1e30f, run_den = 0.f;
  float a0 = 0.f, a1 = 0.f, a2 = 0.f, a3 = 0.f;
  for (int c0 = beg; c0 < end; c0 += 64) {
    int j = c0 + lane;
    float al = -1e30f;
    int sj = 0;
    if (j < end) {
      int e = elist[j];
      sj = src[e];
      float a = sArr[sj] + dnode + aeArr[e];
      al = (a > 0.f) ? a : 0.2f * a;
    }
    float cm = al;
    #pragma unroll
    for (int off = 32; off; off >>= 1) cm = fmaxf(cm, __shfl_xor(cm, off, 64));
    float new_m = fmaxf(run_m, cm);
    float ev = (j < end) ? expf(al - new_m) : 0.f;
    float csum = ev;
    #pragma unroll
    for (int off = 32; off; off >>= 1) csum += __shfl_xor(csum, off, 64);
    float scale = expf(run_m - new_m);
    run_den = run_den * scale + csum;
    a0 *= scale; a1 *= scale; a2 *= scale; a3 *= scale;
    int cdeg = end - c0;
    if (cdeg > 64) cdeg = 64;
    for (int q = 0; q < cdeg; ++q) {
      float wgt = __shfl(ev, q, 64);
      int sq = __shfl(sj, q, 64);
      us4 v = *(const us4*)(xlb + (size_t)sq * HDIM + lane * 4);
      a0 += wgt * bf2f(v[0]); a1 += wgt * bf2f(v[1]);
      a2 += wgt * bf2f(v[2]); a3 += wgt * bf2f(v[3]);
    }
    run_m = new_m;
  }
  float inv = (end > beg) ? 1.f / run_den : 0.f;
  float4 bv = *(const float4*)(bias + lane * 4);
  float o0 = a0 * inv + bv.x, o1 = a1 * inv + bv.y;
  float o2 = a2 * inv + bv.z, o3 = a3 * inv + bv.w;
  if (RELU) {
    o0 = fmaxf(o0, 0.f); o1 = fmaxf(o1, 0.f);
    o2 = fmaxf(o2, 0.f); o3 = fmaxf(o3, 0.f);
  }
  if (OUTBF) {
    us4 ov;
    ov[0] = f2bf(o0); ov[1] = f2bf(o1); ov[2] = f2bf(o2); ov[3] = f2bf(o3);
    *(us4*)((unsigned short*)outv + (size_t)node * HDIM + lane * 4) = ov;
  } else {
    *(float4*)((float*)outv + (size_t)node * HDIM + lane * 4) =
        make_float4(o0, o1, o2, o3);
  }
}

// ---------------- prediction head ----------------

__global__ void k_head(const float* __restrict__ titles, const int* __restrict__ nodes,
                       const float* __restrict__ Wp, const float* __restrict__ bp,
                       float* __restrict__ out, int Bn) {
  int b = blockIdx.x * 4 + (threadIdx.x >> 6);
  if (b >= Bn) return;
  int lane = threadIdx.x & 63;
  const float* r0 = titles + (size_t)nodes[b] * HDIM;
  const float* r1 = titles + (size_t)nodes[Bn + b] * HDIM;
  float s0 = 0.f, s1 = 0.f, s2 = 0.f;
  #pragma unroll
  for (int i = 0; i < 4; ++i) {
    int h = lane + 64 * i;
    float c = r0[h] * r1[h];
    s0 += c * Wp[h * 3 + 0];
    s1 += c * Wp[h * 3 + 1];
    s2 += c * Wp[h * 3 + 2];
  }
  #pragma unroll
  for (int off = 32; off; off >>= 1) {
    s0 += __shfl_down(s0, off, 64);
    s1 += __shfl_down(s1, off, 64);
    s2 += __shfl_down(s2, off, 64);
  }
  if (lane == 0) {
    out[b * 3 + 0] = s0 + bp[0];
    out[b * 3 + 1] = s1 + bp[1];
    out[b * 3 + 2] = s2 + bp[2];
  }
}

// ---------------- launch ----------------

extern "C" void kernel_launch(void* const* d_in, const int* in_sizes, int n_in,
                              void* d_out, int out_size, void* d_ws, size_t ws_size,
                              hipStream_t stream) {
  const float* x         = (const float*)d_in[0];
  const float* edge_attr = (const float*)d_in[1];
  const float* W1  = (const float*)d_in[2];
  const float* as1 = (const float*)d_in[3];
  const float* ad1 = (const float*)d_in[4];
  const float* We1 = (const float*)d_in[5];
  const float* ae1 = (const float*)d_in[6];
  const float* b1  = (const float*)d_in[7];
  const float* W2  = (const float*)d_in[8];
  const float* as2 = (const float*)d_in[9];
  const float* ad2 = (const float*)d_in[10];
  const float* We2 = (const float*)d_in[11];
  const float* ae2 = (const float*)d_in[12];
  const float* b2  = (const float*)d_in[13];
  const float* Wp  = (const float*)d_in[14];
  const float* bp  = (const float*)d_in[15];
  const int* edge_index = (const int*)d_in[16];
  const int* nodes      = (const int*)d_in[17];

  const int N  = in_sizes[0] / FDIM;
  const int E  = in_sizes[16] / 2;
  const int Bn = in_sizes[17] / 2;
  const int* srcArr = edge_index;
  const int* dstArr = edge_index + E;

  char* w = (char*)d_ws;
  auto carve = [&](size_t bytes) -> void* {
    void* p = (void*)w;
    w += (bytes + 255) & ~(size_t)255;
    return p;
  };
  float*          titles = (float*)carve(sizeof(float) * (size_t)N * HDIM);
  unsigned short* xl1b   = (unsigned short*)carve(2 * (size_t)N * HDIM);  // also xl2b
  unsigned short* hb     = (unsigned short*)carve(2 * (size_t)N * HDIM);
  unsigned short* W1t    = (unsigned short*)carve(2 * (size_t)FDIM * HDIM);
  unsigned short* W2t    = (unsigned short*)carve(2 * (size_t)HDIM * HDIM);
  float* ae1Arr = (float*)carve(sizeof(float) * E);
  float* ae2Arr = (float*)carve(sizeof(float) * E);
  float* sArr = (float*)carve(sizeof(float) * N);
  float* dArr = (float*)carve(sizeof(float) * N);
  float* v1 = (float*)carve(sizeof(float) * FDIM);
  float* v2 = (float*)carve(sizeof(float) * FDIM);
  int* cnt     = (int*)carve(sizeof(int) * N);
  int* offsets = (int*)carve(sizeof(int) * (N + 1));
  int* cursor  = (int*)carve(sizeof(int) * N);
  int* elist   = (int*)carve(sizeof(int) * E);
  int* bsums   = (int*)carve(sizeof(int) * 256);

  const int nbScan = (N + 255) / 256;
  const int nbHist = (E + 255) / 256;
  const int nGemm = (N + BM - 1) / BM;
  const int nEdge = (E + 7) / 8;

  // prep (compute_v + cvtW + hist) — hist needs zeroed cnt first
  hipMemsetAsync(cnt, 0, sizeof(int) * N, stream);
  k_prep<<<896 + nbHist, 256, 0, stream>>>(We1, ae1, We2, ae2, v1, v2,
                                           W1, W1t, W2, W2t, dstArr, cnt, E);
  // CSR scan chain (scan2 merged into scan23)
  k_scan1<<<nbScan, 256, 0, stream>>>(cnt, offsets, bsums, N);
  k_scan23<<<nbScan, 256, 0, stream>>>(offsets, cursor, bsums, N);
  k_scatter<<<nbHist, 256, 0, stream>>>(dstArr, cursor, elist, E);

  // fat: GEMM1 (+row-dots, bf16 C) || edge-alpha (both layers)
  k_fat1<<<nGemm + nEdge, 512, 0, stream>>>(x, W1t, xl1b, sArr, dArr, as1, ad1, N,
                                            edge_attr, v1, v2, ae1Arr, ae2Arr, E, nGemm);
  // layer 1 aggregate (bf16 gather) -> hb (bf16)
  k_aggregate<1, 1><<<(N + 3) / 4, 256, 0, stream>>>(xl1b, sArr, dArr, ae1Arr, srcArr,
                                                     offsets, elist, b1, hb, N);
  // layer 2 (xl2 bf16, aliases xl1b buffer — xl1b is dead after agg1)
  k_gemm2<<<nGemm, 512, 0, stream>>>(hb, W2t, xl1b, sArr, dArr, as2, ad2, N);
  k_aggregate<0, 0><<<(N + 3) / 4, 256, 0, stream>>>(xl1b, sArr, dArr, ae2Arr, srcArr,
                                                     offsets, elist, b2, titles, N);
  // head
  k_head<<<(Bn + 3) / 4, 256, 0, stream>>>(titles, nodes, Wp, bp, (float*)d_out, Bn);
}

// Round 7
// 289.891 us; speedup vs baseline: 1.5108x; 1.1091x over previous
//
#include <hip/hip_runtime.h>
#include <math.h>

#define HDIM 256
#define FDIM 768
#define BM 128
#define BK 32

typedef __attribute__((ext_vector_type(8))) short short8;
typedef __attribute__((ext_vector_type(4))) float f32x4;
typedef __attribute__((ext_vector_type(4))) unsigned short us4;

__device__ __forceinline__ unsigned short f2bf(float f) {
  unsigned int u = __float_as_uint(f);
  unsigned int r = (u + 0x7FFFu + ((u >> 16) & 1u)) >> 16;
  return (unsigned short)r;
}
__device__ __forceinline__ float bf2f(unsigned short b) {
  return __uint_as_float(((unsigned int)b) << 16);
}

__device__ __forceinline__ void gload_lds16(const void* g, void* l) {
  __builtin_amdgcn_global_load_lds(
      (const __attribute__((address_space(1))) void*)g,
      (__attribute__((address_space(3))) void*)l, 16, 0, 0);
}

// ---------------- CSR build ----------------

__global__ void k_scan1(const int* __restrict__ cnt, int* __restrict__ offsets,
                        int* __restrict__ bsums, int n) {
  __shared__ int s[256];
  int i = blockIdx.x * 256 + threadIdx.x;
  int v = (i < n) ? cnt[i] : 0;
  s[threadIdx.x] = v;
  __syncthreads();
  for (int off = 1; off < 256; off <<= 1) {
    int t = (threadIdx.x >= off) ? s[threadIdx.x - off] : 0;
    __syncthreads();
    s[threadIdx.x] += t;
    __syncthreads();
  }
  if (i < n) offsets[i + 1] = s[threadIdx.x];
  if (threadIdx.x == 255) bsums[blockIdx.x] = s[255];
}

// merged: every block redundantly scans bsums (nb<=256), then applies its base
// and writes final offsets + cursor.
__global__ void k_scan23(int* __restrict__ offsets, int* __restrict__ cursor,
                         const int* __restrict__ bsums, int n) {
  __shared__ int s2[256];
  __shared__ int sBase;
  const int nb = (n + 255) / 256;
  const int t = threadIdx.x;
  const int bid = blockIdx.x;
  int vv = (t < nb) ? bsums[t] : 0;
  s2[t] = vv;
  __syncthreads();
  for (int off = 1; off < 256; off <<= 1) {
    int tv = (t >= off) ? s2[t - off] : 0;
    __syncthreads();
    s2[t] += tv;
    __syncthreads();
  }
  if (t == 0) sBase = (bid > 0) ? s2[bid - 1] : 0;
  __syncthreads();
  int base = sBase;
  int i = bid * 256 + t;
  if (i < n) {
    int v = offsets[i + 1] + base;
    offsets[i + 1] = v;
    if (i + 1 < n) cursor[i + 1] = v;
    if (i == 0) { offsets[0] = 0; cursor[0] = 0; }
  }
}

__global__ void k_scatter(const int* __restrict__ dst, int* __restrict__ cursor,
                          int* __restrict__ elist, int E) {
  int e = blockIdx.x * 256 + threadIdx.x;
  if (e < E) {
    int p = atomicAdd(&cursor[dst[e]], 1);
    elist[p] = e;
  }
}

// ---------------- prep: compute_v + cvtW1 + cvtW2 + hist, one dispatch ----------------

__global__ __launch_bounds__(256) void k_prep(
    const float* __restrict__ We1, const float* __restrict__ ae1,
    const float* __restrict__ We2, const float* __restrict__ ae2,
    float* __restrict__ v1, float* __restrict__ v2,
    const float* __restrict__ W1, unsigned short* __restrict__ W1t,
    const float* __restrict__ W2, unsigned short* __restrict__ W2t,
    const int* __restrict__ dstArr, int* __restrict__ cnt, int E) {
  int bid = blockIdx.x;
  if (bid < 384) {
    int row = bid * 4 + (threadIdx.x >> 6);
    int lane = threadIdx.x & 63;
    const float* W = (row < FDIM) ? We1 : We2;
    const float* a = (row < FDIM) ? ae1 : ae2;
    int r = (row < FDIM) ? row : row - FDIM;
    float4 w = *(const float4*)&W[(size_t)r * HDIM + lane * 4];
    float4 av = *(const float4*)&a[lane * 4];
    float p = w.x * av.x + w.y * av.y + w.z * av.z + w.w * av.w;
    #pragma unroll
    for (int off = 32; off; off >>= 1) p += __shfl_down(p, off, 64);
    if (lane == 0) ((row < FDIM) ? v1 : v2)[r] = p;
  } else if (bid < 640) {
    int nn = bid - 384;
    for (int k = threadIdx.x; k < FDIM; k += 256)
      W1t[(size_t)nn * FDIM + k] = f2bf(W1[(size_t)k * HDIM + nn]);
  } else if (bid < 896) {
    int nn = bid - 640;
    for (int k = threadIdx.x; k < HDIM; k += 256)
      W2t[(size_t)nn * HDIM + k] = f2bf(W2[(size_t)k * HDIM + nn]);
  } else {
    int e = (bid - 896) * 256 + threadIdx.x;
    if (e < E) atomicAdd(&cnt[dstArr[e]], 1);
  }
}

// ---------------- GEMM body: C[M][HDIM] = A@Bt^T, fused row-dots ----------------

template <bool AF32, bool COUTBF>
__device__ __forceinline__ void gemm_body(unsigned char* lds,
                                          const void* __restrict__ Ain,
                                          const unsigned short* __restrict__ Bt,
                                          void* __restrict__ Cout,
                                          float* __restrict__ sOut,
                                          float* __restrict__ dOut,
                                          const float* __restrict__ a_src,
                                          const float* __restrict__ a_dst,
                                          int M, int K, int tile) {
  unsigned char* As = lds;
  unsigned char* Bs = lds + 8192;
  float* partS = (float*)(lds + 24576);         // [4][128]
  float* partD = (float*)(lds + 24576 + 2048);  // [4][128]
  const int t = threadIdx.x;
  const int l = t & 63;
  const int w = t >> 6;
  const int wm = w >> 2, wn = w & 3;
  const int bm = tile * BM;

  f32x4 acc[4][4] = {};

  int rowA = bm + (t & 127);
  if (rowA >= M) rowA = M - 1;
  const int cA = t >> 7;
  int rowAr = bm + (t >> 2);
  if (rowAr >= M) rowAr = M - 1;
  const int kbAr = t & 3;
  const int sAr = kbAr * 2048 + (t >> 2) * 16;
  const int nB = t & 255;
  const int cB0 = t >> 8;
  const int cB1 = 2 + (t >> 8);

  int aAddr[4], bAddr[4];
  #pragma unroll
  for (int mt = 0; mt < 4; ++mt) {
    int m = wm * 64 + mt * 16 + (l & 15);
    aAddr[mt] = (l >> 4) * 2048 + m * 16;
  }
  #pragma unroll
  for (int nt = 0; nt < 4; ++nt) {
    int nn = wn * 64 + nt * 16 + (l & 15);
    bAddr[nt] = (l >> 4) * 4096 + nn * 16;
  }

  const int nsteps = K / BK;
  for (int ks = 0; ks < nsteps; ++ks) {
    const int k0 = ks * BK;
    __syncthreads();
    if (AF32) {
      const float* A = (const float*)Ain;
      const float* p = A + (size_t)rowAr * K + k0 + kbAr * 8;
      float4 f0 = *(const float4*)p;
      float4 f1 = *(const float4*)(p + 4);
      short8 hv;
      hv[0] = (short)f2bf(f0.x); hv[1] = (short)f2bf(f0.y);
      hv[2] = (short)f2bf(f0.z); hv[3] = (short)f2bf(f0.w);
      hv[4] = (short)f2bf(f1.x); hv[5] = (short)f2bf(f1.y);
      hv[6] = (short)f2bf(f1.z); hv[7] = (short)f2bf(f1.w);
      *(short8*)(As + sAr) = hv;
    } else {
      const unsigned short* A = (const unsigned short*)Ain;
      gload_lds16(A + (size_t)rowA * K + k0 + cA * 8, As + t * 16);
    }
    gload_lds16(Bt + (size_t)nB * K + k0 + cB0 * 8, Bs + t * 16);
    gload_lds16(Bt + (size_t)nB * K + k0 + cB1 * 8, Bs + 8192 + t * 16);
    __syncthreads();

    short8 af[4], bfr[4];
    #pragma unroll
    for (int mt = 0; mt < 4; ++mt) af[mt] = *(const short8*)(As + aAddr[mt]);
    #pragma unroll
    for (int nt = 0; nt < 4; ++nt) bfr[nt] = *(const short8*)(Bs + bAddr[nt]);
    #pragma unroll
    for (int mt = 0; mt < 4; ++mt)
      #pragma unroll
      for (int nt = 0; nt < 4; ++nt)
        acc[mt][nt] = __builtin_amdgcn_mfma_f32_16x16x32_bf16(af[mt], bfr[nt], acc[mt][nt], 0, 0, 0);
  }

  float asv[4], adv[4];
  #pragma unroll
  for (int nt = 0; nt < 4; ++nt) {
    int col = wn * 64 + nt * 16 + (l & 15);
    asv[nt] = a_src[col];
    adv[nt] = a_dst[col];
  }
  #pragma unroll
  for (int mt = 0; mt < 4; ++mt) {
    int rloc = wm * 64 + mt * 16 + ((l >> 4) << 2);
    #pragma unroll
    for (int r = 0; r < 4; ++r) {
      int row = bm + rloc + r;
      float ps = 0.f, pd = 0.f;
      #pragma unroll
      for (int nt = 0; nt < 4; ++nt) {
        float v = acc[mt][nt][r];
        if (row < M) {
          int col = wn * 64 + nt * 16 + (l & 15);
          if (COUTBF)
            ((unsigned short*)Cout)[(size_t)row * HDIM + col] = f2bf(v);
          else
            ((float*)Cout)[(size_t)row * HDIM + col] = v;
        }
        ps += v * asv[nt];
        pd += v * adv[nt];
      }
      #pragma unroll
      for (int off = 1; off < 16; off <<= 1) {
        ps += __shfl_xor(ps, off, 64);
        pd += __shfl_xor(pd, off, 64);
      }
      if ((l & 15) == 0) {
        partS[wn * 128 + rloc + r] = ps;
        partD[wn * 128 + rloc + r] = pd;
      }
    }
  }
  __syncthreads();
  if (t < 128) {
    int row = bm + t;
    if (row < M) {
      sOut[row] = partS[t] + partS[128 + t] + partS[256 + t] + partS[384 + t];
      dOut[row] = partD[t] + partD[128 + t] + partD[256 + t] + partD[384 + t];
    }
  }
}

// ---------------- edge-alpha body (8 edges per 512-thread block) ----------------

__device__ __forceinline__ void edge_body(unsigned char* lds,
                                          const float* __restrict__ ea,
                                          const float* __restrict__ v1,
                                          const float* __restrict__ v2,
                                          float* __restrict__ o1,
                                          float* __restrict__ o2, int E, int ebid) {
  float* sv1 = (float*)lds;
  float* sv2 = (float*)(lds + 3072);
  for (int i = threadIdx.x; i < FDIM; i += 512) { sv1[i] = v1[i]; sv2[i] = v2[i]; }
  __syncthreads();
  int e = ebid * 8 + (threadIdx.x >> 6);
  if (e >= E) return;
  int lane = threadIdx.x & 63;
  const float* row = ea + (size_t)e * FDIM;
  float p1 = 0.f, p2 = 0.f;
  #pragma unroll
  for (int t = 0; t < 3; ++t) {
    int idx = t * 256 + lane * 4;
    float4 x = *(const float4*)&row[idx];
    float4 a = *(const float4*)&sv1[idx];
    float4 b = *(const float4*)&sv2[idx];
    p1 += x.x * a.x + x.y * a.y + x.z * a.z + x.w * a.w;
    p2 += x.x * b.x + x.y * b.y + x.z * b.z + x.w * b.w;
  }
  #pragma unroll
  for (int off = 32; off; off >>= 1) {
    p1 += __shfl_down(p1, off, 64);
    p2 += __shfl_down(p2, off, 64);
  }
  if (lane == 0) { o1[e] = p1; o2[e] = p2; }
}

// ---------------- fat kernel 1: GEMM1 tiles || edge-alpha blocks ----------------

__global__ __launch_bounds__(512) void k_fat1(
    const float* __restrict__ x, const unsigned short* __restrict__ W1t,
    unsigned short* __restrict__ xl1b, float* __restrict__ sArr, float* __restrict__ dArr,
    const float* __restrict__ as1, const float* __restrict__ ad1, int M,
    const float* __restrict__ ea, const float* __restrict__ v1,
    const float* __restrict__ v2, float* __restrict__ ae1Arr,
    float* __restrict__ ae2Arr, int E, int nGemm) {
  __shared__ unsigned char lds[28672];
  if ((int)blockIdx.x < nGemm)
    gemm_body<true, true>(lds, x, W1t, xl1b, sArr, dArr, as1, ad1, M, FDIM, blockIdx.x);
  else
    edge_body(lds, ea, v1, v2, ae1Arr, ae2Arr, E, blockIdx.x - nGemm);
}

__global__ __launch_bounds__(512) void k_gemm2(
    const unsigned short* __restrict__ hb, const unsigned short* __restrict__ W2t,
    unsigned short* __restrict__ xl2b, float* __restrict__ sArr, float* __restrict__ dArr,
    const float* __restrict__ as2, const float* __restrict__ ad2, int M) {
  __shared__ unsigned char lds[28672];
  gemm_body<false, true>(lds, hb, W2t, xl2b, sArr, dArr, as2, ad2, M, HDIM, blockIdx.x);
}

// ---------------- shared per-node aggregation body (one wave, online softmax) ----------------
// returns softmax-weighted gather of xlb rows (4 dims per lane), WITHOUT bias.

__device__ __forceinline__ void agg_node(const unsigned short* __restrict__ xlb,
                                         const float* __restrict__ sArr,
                                         float dnode,
                                         const float* __restrict__ aeArr,
                                         const int* __restrict__ src,
                                         const int* __restrict__ elist,
                                         int beg, int end, int lane,
                                         float& a0, float& a1, float& a2, float& a3) {
  float run_m = -1e30f, run_den = 0.f;
  a0 = a1 = a2 = a3 = 0.f;
  for (int c0 = beg; c0 < end; c0 += 64) {
    int j = c0 + lane;
    float al = -1e30f;
    int sj = 0;
    if (j < end) {
      int e = elist[j];
      sj = src[e];
      float a = sArr[sj] + dnode + aeArr[e];
      al = (a > 0.f) ? a : 0.2f * a;
    }
    float cm = al;
    #pragma unroll
    for (int off = 32; off; off >>= 1) cm = fmaxf(cm, __shfl_xor(cm, off, 64));
    float new_m = fmaxf(run_m, cm);
    float ev = (j < end) ? expf(al - new_m) : 0.f;
    float csum = ev;
    #pragma unroll
    for (int off = 32; off; off >>= 1) csum += __shfl_xor(csum, off, 64);
    float scale = expf(run_m - new_m);
    run_den = run_den * scale + csum;
    a0 *= scale; a1 *= scale; a2 *= scale; a3 *= scale;
    int cdeg = end - c0;
    if (cdeg > 64) cdeg = 64;
    for (int q = 0; q < cdeg; ++q) {
      float wgt = __shfl(ev, q, 64);
      int sq = __shfl(sj, q, 64);
      us4 v = *(const us4*)(xlb + (size_t)sq * HDIM + lane * 4);
      a0 += wgt * bf2f(v[0]); a1 += wgt * bf2f(v[1]);
      a2 += wgt * bf2f(v[2]); a3 += wgt * bf2f(v[3]);
    }
    run_m = new_m;
  }
  float inv = (end > beg) ? 1.f / run_den : 0.f;
  a0 *= inv; a1 *= inv; a2 *= inv; a3 *= inv;
}

// ---------------- layer-1 aggregate (all nodes, relu, bf16 out) ----------------

__global__ __launch_bounds__(256) void k_aggregate1(const unsigned short* __restrict__ xlb,
                                                    const float* __restrict__ sArr,
                                                    const float* __restrict__ dArr,
                                                    const float* __restrict__ aeArr,
                                                    const int* __restrict__ src,
                                                    const int* __restrict__ offsets,
                                                    const int* __restrict__ elist,
                                                    const float* __restrict__ bias,
                                                    unsigned short* __restrict__ outb,
                                                    int n) {
  int node = blockIdx.x * 4 + (threadIdx.x >> 6);
  if (node >= n) return;
  int lane = threadIdx.x & 63;
  int beg = offsets[node], end = offsets[node + 1];
  float a0, a1, a2, a3;
  agg_node(xlb, sArr, dArr[node], aeArr, src, elist, beg, end, lane, a0, a1, a2, a3);
  float4 bv = *(const float4*)(bias + lane * 4);
  float o0 = fmaxf(a0 + bv.x, 0.f), o1 = fmaxf(a1 + bv.y, 0.f);
  float o2 = fmaxf(a2 + bv.z, 0.f), o3 = fmaxf(a3 + bv.w, 0.f);
  us4 ov;
  ov[0] = f2bf(o0); ov[1] = f2bf(o1); ov[2] = f2bf(o2); ov[3] = f2bf(o3);
  *(us4*)(outb + (size_t)node * HDIM + lane * 4) = ov;
}

// ---------------- fused layer-2 aggregate (pair nodes only) + head ----------------
// 256 threads = 4 waves = 2 pairs; wave (p,side) aggregates titles[node] into regs,
// exchanges via LDS, side-0 wave computes (t0*t1)@Wp + bp.

__global__ __launch_bounds__(256) void k_agg2head(const unsigned short* __restrict__ xl2b,
                                                  const float* __restrict__ sArr,
                                                  const float* __restrict__ dArr,
                                                  const float* __restrict__ aeArr,
                                                  const int* __restrict__ src,
                                                  const int* __restrict__ offsets,
                                                  const int* __restrict__ elist,
                                                  const float* __restrict__ b2,
                                                  const int* __restrict__ nodes,
                                                  const float* __restrict__ Wp,
                                                  const float* __restrict__ bp,
                                                  float* __restrict__ out, int Bn) {
  __shared__ float tls[2][2][HDIM];
  int wv = threadIdx.x >> 6;
  int lane = threadIdx.x & 63;
  int pl = wv >> 1;    // pair within block
  int side = wv & 1;
  int b = blockIdx.x * 2 + pl;
  if (b < Bn) {
    int node = nodes[side * Bn + b];
    int beg = offsets[node], end = offsets[node + 1];
    float a0, a1, a2, a3;
    agg_node(xl2b, sArr, dArr[node], aeArr, src, elist, beg, end, lane, a0, a1, a2, a3);
    float4 bv = *(const float4*)(b2 + lane * 4);
    float* dstp = &tls[pl][side][lane * 4];
    dstp[0] = a0 + bv.x; dstp[1] = a1 + bv.y;
    dstp[2] = a2 + bv.z; dstp[3] = a3 + bv.w;
  }
  __syncthreads();
  if (b < Bn && side == 0) {
    float4 t0 = *(const float4*)&tls[pl][0][lane * 4];
    float4 t1 = *(const float4*)&tls[pl][1][lane * 4];
    float c0 = t0.x * t1.x, c1 = t0.y * t1.y, c2 = t0.z * t1.z, c3 = t0.w * t1.w;
    int h0 = lane * 4;
    float s0 = c0 * Wp[h0 * 3 + 0] + c1 * Wp[(h0 + 1) * 3 + 0] +
               c2 * Wp[(h0 + 2) * 3 + 0] + c3 * Wp[(h0 + 3) * 3 + 0];
    float s1 = c0 * Wp[h0 * 3 + 1] + c1 * Wp[(h0 + 1) * 3 + 1] +
               c2 * Wp[(h0 + 2) * 3 + 1] + c3 * Wp[(h0 + 3) * 3 + 1];
    float s2 = c0 * Wp[h0 * 3 + 2] + c1 * Wp[(h0 + 1) * 3 + 2] +
               c2 * Wp[(h0 + 2) * 3 + 2] + c3 * Wp[(h0 + 3) * 3 + 2];
    #pragma unroll
    for (int off = 32; off; off >>= 1) {
      s0 += __shfl_down(s0, off, 64);
      s1 += __shfl_down(s1, off, 64);
      s2 += __shfl_down(s2, off, 64);
    }
    if (lane == 0) {
      out[b * 3 + 0] = s0 + bp[0];
      out[b * 3 + 1] = s1 + bp[1];
      out[b * 3 + 2] = s2 + bp[2];
    }
  }
}

// ---------------- launch ----------------

extern "C" void kernel_launch(void* const* d_in, const int* in_sizes, int n_in,
                              void* d_out, int out_size, void* d_ws, size_t ws_size,
                              hipStream_t stream) {
  const float* x         = (const float*)d_in[0];
  const float* edge_attr = (const float*)d_in[1];
  const float* W1  = (const float*)d_in[2];
  const float* as1 = (const float*)d_in[3];
  const float* ad1 = (const float*)d_in[4];
  const float* We1 = (const float*)d_in[5];
  const float* ae1 = (const float*)d_in[6];
  const float* b1  = (const float*)d_in[7];
  const float* W2  = (const float*)d_in[8];
  const float* as2 = (const float*)d_in[9];
  const float* ad2 = (const float*)d_in[10];
  const float* We2 = (const float*)d_in[11];
  const float* ae2 = (const float*)d_in[12];
  const float* b2  = (const float*)d_in[13];
  const float* Wp  = (const float*)d_in[14];
  const float* bp  = (const float*)d_in[15];
  const int* edge_index = (const int*)d_in[16];
  const int* nodes      = (const int*)d_in[17];

  const int N  = in_sizes[0] / FDIM;
  const int E  = in_sizes[16] / 2;
  const int Bn = in_sizes[17] / 2;
  const int* srcArr = edge_index;
  const int* dstArr = edge_index + E;

  char* w = (char*)d_ws;
  auto carve = [&](size_t bytes) -> void* {
    void* p = (void*)w;
    w += (bytes + 255) & ~(size_t)255;
    return p;
  };
  unsigned short* xl1b   = (unsigned short*)carve(2 * (size_t)N * HDIM);  // also xl2b
  unsigned short* hb     = (unsigned short*)carve(2 * (size_t)N * HDIM);
  unsigned short* W1t    = (unsigned short*)carve(2 * (size_t)FDIM * HDIM);
  unsigned short* W2t    = (unsigned short*)carve(2 * (size_t)HDIM * HDIM);
  float* ae1Arr = (float*)carve(sizeof(float) * E);
  float* ae2Arr = (float*)carve(sizeof(float) * E);
  float* sArr = (float*)carve(sizeof(float) * N);
  float* dArr = (float*)carve(sizeof(float) * N);
  float* v1 = (float*)carve(sizeof(float) * FDIM);
  float* v2 = (float*)carve(sizeof(float) * FDIM);
  int* cnt     = (int*)carve(sizeof(int) * N);
  int* offsets = (int*)carve(sizeof(int) * (N + 1));
  int* cursor  = (int*)carve(sizeof(int) * N);
  int* elist   = (int*)carve(sizeof(int) * E);
  int* bsums   = (int*)carve(sizeof(int) * 256);

  const int nbScan = (N + 255) / 256;
  const int nbHist = (E + 255) / 256;
  const int nGemm = (N + BM - 1) / BM;
  const int nEdge = (E + 7) / 8;

  hipMemsetAsync(cnt, 0, sizeof(int) * N, stream);
  k_prep<<<896 + nbHist, 256, 0, stream>>>(We1, ae1, We2, ae2, v1, v2,
                                           W1, W1t, W2, W2t, dstArr, cnt, E);
  k_scan1<<<nbScan, 256, 0, stream>>>(cnt, offsets, bsums, N);
  k_scan23<<<nbScan, 256, 0, stream>>>(offsets, cursor, bsums, N);
  k_scatter<<<nbHist, 256, 0, stream>>>(dstArr, cursor, elist, E);

  // fat: GEMM1 (+row-dots, bf16 C) || edge-alpha (both layers)
  k_fat1<<<nGemm + nEdge, 512, 0, stream>>>(x, W1t, xl1b, sArr, dArr, as1, ad1, N,
                                            edge_attr, v1, v2, ae1Arr, ae2Arr, E, nGemm);
  // layer 1 aggregate (bf16 gather) -> hb (bf16)
  k_aggregate1<<<(N + 3) / 4, 256, 0, stream>>>(xl1b, sArr, dArr, ae1Arr, srcArr,
                                                offsets, elist, b1, hb, N);
  // layer 2 GEMM (xl2 bf16, aliases xl1b buffer)
  k_gemm2<<<nGemm, 512, 0, stream>>>(hb, W2t, xl1b, sArr, dArr, as2, ad2, N);
  // fused layer-2 aggregate (pair nodes only) + head
  k_agg2head<<<(Bn + 1) / 2, 256, 0, stream>>>(xl1b, sArr, dArr, ae2Arr, srcArr,
                                               offsets, elist, b2, nodes, Wp, bp,
                                               (float*)d_out, Bn);
}